// Round 5
// baseline (149.246 us; speedup 1.0000x reference)
//
#include <hip/hip_runtime.h>
#include <math.h>

#define BQ 8
#define MQ 64
#define KTOP 10
#define EPSQ 1e-7f
#define APB 256   // anchors per decode block (256 threads x 1) -> 1064 blocks
#define MBUF 1344 // >= bpb*KTOP = 1330 for N=34000

__device__ __forceinline__ float frcp(float x) { return __builtin_amdgcn_rcpf(x); }

// softmax expected-value over 16 named scalars
#define EV16(G, OUT)                                                           \
  {                                                                            \
    float mx = fmaxf(fmaxf(fmaxf(fmaxf(G##0, G##1), fmaxf(G##2, G##3)),        \
                           fmaxf(fmaxf(G##4, G##5), fmaxf(G##6, G##7))),       \
                     fmaxf(fmaxf(fmaxf(G##8, G##9), fmaxf(G##10, G##11)),      \
                           fmaxf(fmaxf(G##12, G##13), fmaxf(G##14, G##15))));  \
    float s = 0.f, ws = 0.f, e;                                                \
    e = __expf(G##0 - mx); s += e;                                             \
    e = __expf(G##1 - mx); s += e; ws += 1.f * e;                              \
    e = __expf(G##2 - mx); s += e; ws += 2.f * e;                              \
    e = __expf(G##3 - mx); s += e; ws += 3.f * e;                              \
    e = __expf(G##4 - mx); s += e; ws += 4.f * e;                              \
    e = __expf(G##5 - mx); s += e; ws += 5.f * e;                              \
    e = __expf(G##6 - mx); s += e; ws += 6.f * e;                              \
    e = __expf(G##7 - mx); s += e; ws += 7.f * e;                              \
    e = __expf(G##8 - mx); s += e; ws += 8.f * e;                              \
    e = __expf(G##9 - mx); s += e; ws += 9.f * e;                              \
    e = __expf(G##10 - mx); s += e; ws += 10.f * e;                            \
    e = __expf(G##11 - mx); s += e; ws += 11.f * e;                            \
    e = __expf(G##12 - mx); s += e; ws += 12.f * e;                            \
    e = __expf(G##13 - mx); s += e; ws += 13.f * e;                            \
    e = __expf(G##14 - mx); s += e; ws += 14.f * e;                            \
    e = __expf(G##15 - mx); s += e; ws += 15.f * e;                            \
    OUT = ws * frcp(s);                                                        \
  }

// 16 values of one side from the LDS tile (lane-consecutive -> conflict-free)
#define DECL_LDS16(RB, G)                                                      \
  float G##0 = tile[(RB) + 0][tid], G##1 = tile[(RB) + 1][tid],                \
        G##2 = tile[(RB) + 2][tid], G##3 = tile[(RB) + 3][tid],                \
        G##4 = tile[(RB) + 4][tid], G##5 = tile[(RB) + 5][tid],                \
        G##6 = tile[(RB) + 6][tid], G##7 = tile[(RB) + 7][tid],                \
        G##8 = tile[(RB) + 8][tid], G##9 = tile[(RB) + 9][tid],                \
        G##10 = tile[(RB) + 10][tid], G##11 = tile[(RB) + 11][tid],            \
        G##12 = tile[(RB) + 12][tid], G##13 = tile[(RB) + 13][tid],            \
        G##14 = tile[(RB) + 14][tid], G##15 = tile[(RB) + 15][tid];

// ---------------- kernel 1: decode via STREAMING LDS staging (coalesced
// contiguous row reads; the 136KB-strided per-thread gather was running at
// ~full latency per load across every prior variant) + screen + top-10 ----------------
__global__ __launch_bounds__(256) void decode_topk_kernel(
    const float* __restrict__ boxes, const float* __restrict__ scores,
    const float* __restrict__ targets, unsigned int* __restrict__ iou_bits,
    uint2* __restrict__ cand, float* __restrict__ bcePartial,
    unsigned int* __restrict__ ctr, int N, int bpb) {
  const int tid = threadIdx.x;
  const int b = blockIdx.x / bpb;
  const int blk = blockIdx.x - b * bpb;
  const int a0 = blk * APB;
  const int w = tid >> 6;
  const int l = tid & 63;

  // 32KB region: phase-1 stage tile ALIASED with phase-2/3 heaps (temporally
  // disjoint, separated by __syncthreads) -> total LDS ~38KB -> 4 blocks/CU.
  __shared__ __align__(16) char u_raw[32 * APB * sizeof(float)];
  float(*tile)[APB] = (float(*)[APB])u_raw;
  float* s_hv = (float*)u_raw;                           // 2560 floats (10240B)
  int* s_hi = (int*)(u_raw + 4 * MQ * KTOP * 4);         // 2560 ints  (10240B)
  uint2* s_mg = (uint2*)(u_raw + 8 * MQ * KTOP * 4);     // 640 uint2  (5120B)

  __shared__ float4 s_sv[APB];
  __shared__ float s_at[APB];
  __shared__ int s_ix[APB];
  __shared__ int s_cnt;
  __shared__ float s_bce;
  if (tid == 0) { s_cnt = 0; s_bce = 0.f; }
  // zero the merge-done counter; decode fully precedes merge (stream order).
  if (blockIdx.x == 0 && tid == 0) *ctr = 0u;
  __syncthreads();

  const size_t Ns = (size_t)N;

  // ---- early per-anchor bookkeeping (overlaps with first stage) ----
  const int n = a0 + tid;
  float bce0 = 0.f;
  if (n < N) {
    const size_t i = (size_t)b * N + n;
    iou_bits[i] = 0u;
    float sc = scores[i];
    bce0 = fmaxf(sc, 0.f) + log1pf(__expf(-fabsf(sc)));
  }

  // stage 32 rows x 256 anchors (32KB): wave reads contiguous 1KB segments
  auto stage32 = [&](int row0) {
    const float* gbase = boxes + (size_t)(b * 64 + row0) * Ns + a0;
    if (a0 + APB <= N) {
#pragma unroll
      for (int k = 0; k < 8; ++k) {
        int idx = tid + (k << 8);
        int r = idx >> 6;
        int c = (idx & 63) << 2;
        *(float4*)&tile[r][c] = *(const float4*)(gbase + (size_t)r * Ns + c);
      }
    } else {
      int rem = N - a0;  // tail block
#pragma unroll
      for (int k = 0; k < 8; ++k) {
        int idx = tid + (k << 8);
        int r = idx >> 6;
        int c = (idx & 63) << 2;
        for (int j = 0; j < 4; ++j)
          tile[r][c + j] = (c + j < rem) ? gbase[(size_t)r * Ns + c + j] : 0.f;
      }
    }
  };

  float e0, e1, e2, e3;
  stage32(0);
  __syncthreads();
  { DECL_LDS16(0, A) EV16(A, e0) }
  { DECL_LDS16(16, Bv) EV16(Bv, e1) }
  __syncthreads();  // all tile reads done before restage
  stage32(32);
  __syncthreads();
  { DECL_LDS16(0, Cv) EV16(Cv, e2) }
  { DECL_LDS16(16, Dv) EV16(Dv, e3) }

  bool pred = false;
  float at = 0.f;
  if (n < N) {
    float w1 = e2 - e0, h1 = e3 - e1;
    if (w1 > 0.f && h1 > 0.f) {  // else ciou<=0 vs every target (ref masks topv>0)
      pred = true;
      at = atanf(w1 * frcp(h1 + EPSQ));
    }
  }
  // ballot compaction: one contended LDS atomic per wave (not per thread)
  {
    unsigned long long mask = __ballot(pred);
    int cnt = __popcll(mask);
    int bslot = 0;
    if (l == 0 && cnt) bslot = atomicAdd(&s_cnt, cnt);
    bslot = __shfl(bslot, 0, 64);
    if (pred) {
      int pos = bslot + __popcll(mask & ((1ull << l) - 1ull));
      s_sv[pos] = make_float4(e0, e1, e2, e3);
      s_at[pos] = at;
      s_ix[pos] = n;
    }
  }
#pragma unroll
  for (int d = 1; d < 64; d <<= 1) bce0 += __shfl_xor(bce0, d, 64);
  if (l == 0) atomicAdd(&s_bce, bce0);
  __syncthreads();  // tile dead from here; heap region (s_hv/s_hi/s_mg) live
  const int nsurv = s_cnt;
  if (tid == 0) bcePartial[blockIdx.x] = s_bce;  // always written: no memset needed

  // ---- phase 2: lane = target; wave w scans its survivor quarter (LDS broadcast) ----
  const float4 t = ((const float4*)targets)[b * MQ + l];
  const float x21 = t.x, y21 = t.y, x22 = t.z, y22 = t.w;
  const float w2 = x22 - x21, h2 = y22 - y21;
  const float atan_t = atanf(w2 * frcp(h2 + EPSQ));
  const float area2 = w2 * h2, sumx2 = x21 + x22, sumy2 = y21 + y22;
  const float CPI = 4.0f / (float)(M_PI * M_PI);

  float hv0 = 0.f, hv1 = 0.f, hv2 = 0.f, hv3 = 0.f, hv4 = 0.f;
  float hv5 = 0.f, hv6 = 0.f, hv7 = 0.f, hv8 = 0.f, hv9 = 0.f;
  int hi0 = 0, hi1 = 0, hi2 = 0, hi3 = 0, hi4 = 0;
  int hi5 = 0, hi6 = 0, hi7 = 0, hi8 = 0, hi9 = 0;

  const int qlen = (nsurv + 3) >> 2;
  const int j0 = w * qlen;
  const int j1 = min(nsurv, j0 + qlen);
  for (int j = j0; j < j1; ++j) {
    float4 p = s_sv[j];  // same addr across lanes -> LDS broadcast
    float pa = s_at[j];
    int ixj = s_ix[j];
    float x11 = p.x, y11 = p.y, x12 = p.z, y12 = p.w;
    float w1 = x12 - x11, h1 = y12 - y11;
    float iw = fmaxf(fminf(x12, x22) - fmaxf(x11, x21), 0.f);
    float ih = fmaxf(fminf(y12, y22) - fmaxf(y11, y21), 0.f);
    float inter = iw * ih;
    float uni = w1 * h1 + area2 - inter + EPSQ;
    float iou = inter * frcp(uni);
    float cw = fmaxf(x12, x22) - fminf(x11, x21);
    float ch = fmaxf(y12, y22) - fminf(y11, y21);
    float c2 = cw * cw + ch * ch + EPSQ;
    float dx = sumx2 - x11 - x12;
    float dy = sumy2 - y11 - y12;
    float rho2 = (dx * dx + dy * dy) * 0.25f;
    float da = atan_t - pa;
    float v = CPI * da * da;
    float alpha = v * frcp(v - iou + 1.f + EPSQ);
    float ciou = iou - rho2 * frcp(c2) - alpha * v;
    if (ciou > hv9) {
      float cv = ciou;
      int ci = ixj;
#define INS(vk, ik)                         \
  {                                         \
    bool gt = cv > vk;                      \
    float tv_ = vk; int ti_ = ik;           \
    vk = gt ? cv : vk; ik = gt ? ci : ik;   \
    cv = gt ? tv_ : cv; ci = gt ? ti_ : ci; \
  }
      INS(hv0, hi0) INS(hv1, hi1) INS(hv2, hi2) INS(hv3, hi3) INS(hv4, hi4)
      INS(hv5, hi5) INS(hv6, hi6) INS(hv7, hi7) INS(hv8, hi8) INS(hv9, hi9)
#undef INS
    }
  }
  const int hb = (w * MQ + l) * KTOP;
  s_hv[hb + 0] = hv0; s_hi[hb + 0] = hi0;
  s_hv[hb + 1] = hv1; s_hi[hb + 1] = hi1;
  s_hv[hb + 2] = hv2; s_hi[hb + 2] = hi2;
  s_hv[hb + 3] = hv3; s_hi[hb + 3] = hi3;
  s_hv[hb + 4] = hv4; s_hi[hb + 4] = hi4;
  s_hv[hb + 5] = hv5; s_hi[hb + 5] = hi5;
  s_hv[hb + 6] = hv6; s_hi[hb + 6] = hi6;
  s_hv[hb + 7] = hv7; s_hi[hb + 7] = hi7;
  s_hv[hb + 8] = hv8; s_hi[hb + 8] = hi8;
  s_hv[hb + 9] = hv9; s_hi[hb + 9] = hi9;
  __syncthreads();

  // ---- phase 3: wave 0, lane m: 4-way merge -> s_mg ----
  if (w == 0) {
    const int m = l;
    int p0 = 0, p1 = 0, p2 = 0, p3 = 0;
    for (int r = 0; r < KTOP; ++r) {
      float c0 = s_hv[(0 * MQ + m) * KTOP + p0];
      float c1 = s_hv[(1 * MQ + m) * KTOP + p1];
      float c2m = s_hv[(2 * MQ + m) * KTOP + p2];
      float c3 = s_hv[(3 * MQ + m) * KTOP + p3];
      float best = c0; int bw = 0;
      if (c1 > best) { best = c1; bw = 1; }
      if (c2m > best) { best = c2m; bw = 2; }
      if (c3 > best) { best = c3; bw = 3; }
      int psel = (bw == 0) ? p0 : (bw == 1) ? p1 : (bw == 2) ? p2 : p3;
      int bidx = s_hi[(bw * MQ + m) * KTOP + psel];
      s_mg[m * KTOP + r] = make_uint2(__float_as_uint(best), (unsigned)bidx);
      if (bw == 0) p0 = min(p0 + 1, KTOP - 1);
      else if (bw == 1) p1 = min(p1 + 1, KTOP - 1);
      else if (bw == 2) p2 = min(p2 + 1, KTOP - 1);
      else p3 = min(p3 + 1, KTOP - 1);
    }
  }
  __syncthreads();
  // copy-out: CONTIGUOUS per-block store (merge takes the strided read side)
  uint2* obase = cand + (size_t)(b * bpb + blk) * (MQ * KTOP);
  for (int sl = tid; sl < MQ * KTOP; sl += 256) obase[sl] = s_mg[sl];
}

// ---------------- exact top-10 of LDS buffer (wave 0 only) ----------------
__device__ __forceinline__ void select_top10(
    float* s_bv, int* s_bi, float* s_winv, int* s_wini,
    int* s_cnt, int c, int tid) {
  if (tid < 64) {
    for (int r = 0; r < KTOP; ++r) {
      float bv = 0.f;
      int bs = 0xffff;
      for (int sl = tid; sl < c; sl += 64) {
        float v = s_bv[sl];
        if (v > bv) { bv = v; bs = sl; }
      }
      unsigned long long key =
          ((unsigned long long)__float_as_uint(bv) << 32) | (unsigned int)bs;
#pragma unroll
      for (int d = 1; d < 64; d <<= 1) {
        unsigned long long o = __shfl_xor(key, d, 64);
        if (o > key) key = o;
      }
      if (tid == 0) {
        float wv = __uint_as_float((unsigned int)(key >> 32));
        int ws = (int)(key & 0xffffu);
        s_winv[r] = wv;
        if (wv > 0.f && ws != 0xffff) {
          s_wini[r] = s_bi[ws];
          s_bv[ws] = 0.f;
        } else {
          s_wini[r] = 0;
        }
      }
    }
    if (tid < KTOP) { s_bv[tid] = s_winv[tid]; s_bi[tid] = s_wini[tid]; }
    if (tid == 0) *s_cnt = KTOP;
  }
}

// ---------------- kernel 2: merge 133x10 per (b,m) -> top-10; scatter + exact delta;
// last block finalizes with a parallel reduction ----------------
__global__ __launch_bounds__(256) void merge_kernel(
    const uint2* __restrict__ cand, const float* __restrict__ scores,
    unsigned int* __restrict__ iou_bits, const float* __restrict__ bcePartial,
    float* __restrict__ mergePartial, unsigned int* __restrict__ ctr,
    float* __restrict__ out, int N, int bpb) {
  const int bm = blockIdx.x;
  const int b = bm >> 6;
  const int m = bm & 63;
  const int tid = threadIdx.x;
  const int l = tid & 63;
  const int NC = bpb * KTOP;  // 1330 for N=34000

  __shared__ float s_bv[MBUF];
  __shared__ int s_bi[MBUF];
  __shared__ float s_winv[KTOP];
  __shared__ int s_wini[KTOP];
  __shared__ int s_cnt;
  __shared__ float s_d[3];
  __shared__ int s_last;
  __shared__ float s_acc[BQ * 3];  // finalize: {box_sum, npos, bce} per batch
  if (tid == 0) s_cnt = 0;
  if (tid < 3) s_d[tid] = 0.f;
  if (tid < BQ * 3) s_acc[tid] = 0.f;
  __syncthreads();

  // strided gather over decode blocks (cand in contiguous-per-block layout)
  for (int k2 = tid; k2 < NC; k2 += 256) {
    int blkk = k2 / KTOP;
    int r = k2 - blkk * KTOP;
    uint2 e = cand[((size_t)(b * bpb + blkk) * MQ + m) * KTOP + r];
    float v = __uint_as_float(e.x);
    bool p = v > 0.f;
    unsigned long long mask = __ballot(p);  // lane0 active whenever any lane is
    int cnt = __popcll(mask);
    int bslot = 0;
    if (l == 0 && cnt) bslot = atomicAdd(&s_cnt, cnt);
    bslot = __shfl(bslot, 0, 64);
    if (p) {
      int pos = bslot + __popcll(mask & ((1ull << l) - 1ull));
      s_bv[pos] = v;
      s_bi[pos] = (int)e.y;
    }
  }
  __syncthreads();
  int c = s_cnt;
  __syncthreads();
  if (c > KTOP) {
    select_top10(s_bv, s_bi, s_winv, s_wini, &s_cnt, c, tid);
    __syncthreads();
    c = KTOP;
  }
  if (tid < KTOP && tid < c) {
    float v = s_bv[tid];
    if (v > 0.f) {
      int ix = s_bi[tid];
      unsigned int vb = __float_as_uint(v);
      unsigned int old = atomicMax(&iou_bits[(size_t)b * N + ix], vb);
      if (old < vb) {  // raised this anchor's max: exact delta (telescopes)
        float vold = __uint_as_float(old);  // 0.f when old==0
        bool was = (old != 0u);
        atomicAdd(&s_d[0], was ? (vold - v) : (1.f - v));
        if (!was) atomicAdd(&s_d[1], 1.f);
        atomicAdd(&s_d[2], -scores[(size_t)b * N + ix] * (v - vold));
      }
    }
  }
  __syncthreads();
  if (tid == 0) {
    float4* mp = (float4*)(mergePartial + (size_t)bm * 4);
    *mp = make_float4(s_d[0], s_d[1], s_d[2], 0.f);  // always written
    __threadfence();                                  // release partials
    unsigned int done = atomicAdd(ctr, 1u);           // device-scope RMW
    s_last = (done == (unsigned)(gridDim.x - 1)) ? 1 : 0;
  }
  __syncthreads();
  if (s_last) {
    __threadfence();  // acquire: all other blocks' partials now visible
    // parallel reduction: 256 threads, MLP across lanes, LDS float atomics.
    volatile const float* mp = mergePartial;
    for (int i = tid; i < BQ * MQ; i += 256) {
      int bb = i >> 6;
      float a0 = mp[i * 4 + 0];
      float a1 = mp[i * 4 + 1];
      float a2 = mp[i * 4 + 2];
      atomicAdd(&s_acc[bb * 3 + 0], a0);
      atomicAdd(&s_acc[bb * 3 + 1], a1);
      atomicAdd(&s_acc[bb * 3 + 2], a2);
    }
    volatile const float* bp = bcePartial;
    for (int i = tid; i < BQ * bpb; i += 256) {
      int bb = i / bpb;
      atomicAdd(&s_acc[bb * 3 + 2], bp[i]);
    }
    __syncthreads();
    if (tid == 0) {
      float box = 0.f, obj = 0.f;
      for (int bb = 0; bb < BQ; ++bb) {
        float np = s_acc[bb * 3 + 1];
        box += (np > 0.f) ? s_acc[bb * 3 + 0] / fmaxf(np, 1.f) : 0.f;
        obj += s_acc[bb * 3 + 2] / (float)N;
      }
      out[0] = (7.5f * box + obj) / (float)BQ;
      out[1] = box;
      out[2] = obj;
    }
  }
}

extern "C" void kernel_launch(void* const* d_in, const int* in_sizes, int n_in,
                              void* d_out, int out_size, void* d_ws, size_t ws_size,
                              hipStream_t stream) {
  const float* boxes = (const float*)d_in[0];
  const float* scores = (const float*)d_in[1];
  const float* targets = (const float*)d_in[2];
  float* out = (float*)d_out;
  const int N = in_sizes[1] / BQ;  // scores is [B, N]

  const int bpb = (N + APB - 1) / APB;  // 133 for N=34000
  const int nblk = BQ * bpb;            // 1064 decode blocks

  char* ws = (char*)d_ws;
  size_t cand_bytes = (size_t)BQ * bpb * MQ * KTOP * sizeof(uint2);
  size_t iou_bytes = (size_t)BQ * N * sizeof(unsigned int);
  size_t bce_bytes = (((size_t)nblk * sizeof(float)) + 255) & ~(size_t)255;
  size_t mp_bytes = (size_t)BQ * MQ * 4 * sizeof(float);

  uint2* cand = (uint2*)ws;                    ws += cand_bytes;
  unsigned int* iou_bits = (unsigned int*)ws;  ws += iou_bytes;
  float* bcePartial = (float*)ws;              ws += bce_bytes;
  float* mergePartial = (float*)ws;            ws += mp_bytes;
  unsigned int* ctr = (unsigned int*)ws;

  // 2 dispatches: no memset (always-written per-block partials; ctr zeroed by
  // decode which fully precedes merge by stream order), no finalize dispatch
  // (folded into merge's last block, parallel-reduced).
  decode_topk_kernel<<<nblk, 256, 0, stream>>>(boxes, scores, targets,
                                               iou_bits, cand, bcePartial, ctr, N, bpb);
  merge_kernel<<<BQ * MQ, 256, 0, stream>>>(cand, scores, iou_bits, bcePartial,
                                            mergePartial, ctr, out, N, bpb);
}

// Round 6
// 144.625 us; speedup vs baseline: 1.0319x; 1.0319x over previous
//
#include <hip/hip_runtime.h>
#include <math.h>

#define BQ 8
#define MQ 64
#define KTOP 10
#define EPSQ 1e-7f
#define APB 256   // anchors per decode block (4 waves x 64 anchors)
#define MBUF 1344 // >= bpb*KTOP = 1330 for N=34000

__device__ __forceinline__ float frcp(float x) { return __builtin_amdgcn_rcpf(x); }

// async global->LDS, 4B/lane: LDS dest = uniform base + lane*4 (HW);
// global src = per-lane address. Tracked by vmcnt.
__device__ __forceinline__ void load_lds_dword(const float* g, void* l) {
  __builtin_amdgcn_global_load_lds(
      (const __attribute__((address_space(1))) void*)g,
      (__attribute__((address_space(3))) void*)l, 4, 0, 0);
}

#define WAITVM(N)                                           \
  asm volatile("s_waitcnt vmcnt(" #N ")" ::: "memory");     \
  __builtin_amdgcn_sched_barrier(0);

#define WAITLGKM()                                          \
  asm volatile("s_waitcnt lgkmcnt(0)" ::: "memory");        \
  __builtin_amdgcn_sched_barrier(0);

// issue 16 row-loads (one side) into a 4KB wave buffer; rows R0..R0+15
#define G16(R0, BUF)                                                     \
  {                                                                      \
    _Pragma("unroll") for (int r = 0; r < 16; ++r)                       \
        load_lds_dword(gl + (size_t)((R0) + r) * Ns, (BUF) + r * 64);    \
    __builtin_amdgcn_sched_barrier(0);                                   \
  }

// 16 values of one side from the wave tile (lane-consecutive -> conflict-free)
#define DECL_B(BUF, G)                                                   \
  float G##0 = (BUF)[0 * 64 + l], G##1 = (BUF)[1 * 64 + l],              \
        G##2 = (BUF)[2 * 64 + l], G##3 = (BUF)[3 * 64 + l],              \
        G##4 = (BUF)[4 * 64 + l], G##5 = (BUF)[5 * 64 + l],              \
        G##6 = (BUF)[6 * 64 + l], G##7 = (BUF)[7 * 64 + l],              \
        G##8 = (BUF)[8 * 64 + l], G##9 = (BUF)[9 * 64 + l],              \
        G##10 = (BUF)[10 * 64 + l], G##11 = (BUF)[11 * 64 + l],          \
        G##12 = (BUF)[12 * 64 + l], G##13 = (BUF)[13 * 64 + l],          \
        G##14 = (BUF)[14 * 64 + l], G##15 = (BUF)[15 * 64 + l];

#define EV16(G, OUT)                                                           \
  {                                                                            \
    float mx = fmaxf(fmaxf(fmaxf(fmaxf(G##0, G##1), fmaxf(G##2, G##3)),        \
                           fmaxf(fmaxf(G##4, G##5), fmaxf(G##6, G##7))),       \
                     fmaxf(fmaxf(fmaxf(G##8, G##9), fmaxf(G##10, G##11)),      \
                           fmaxf(fmaxf(G##12, G##13), fmaxf(G##14, G##15))));  \
    float s = 0.f, ws = 0.f, e;                                                \
    e = __expf(G##0 - mx); s += e;                                             \
    e = __expf(G##1 - mx); s += e; ws += 1.f * e;                              \
    e = __expf(G##2 - mx); s += e; ws += 2.f * e;                              \
    e = __expf(G##3 - mx); s += e; ws += 3.f * e;                              \
    e = __expf(G##4 - mx); s += e; ws += 4.f * e;                              \
    e = __expf(G##5 - mx); s += e; ws += 5.f * e;                              \
    e = __expf(G##6 - mx); s += e; ws += 6.f * e;                              \
    e = __expf(G##7 - mx); s += e; ws += 7.f * e;                              \
    e = __expf(G##8 - mx); s += e; ws += 8.f * e;                              \
    e = __expf(G##9 - mx); s += e; ws += 9.f * e;                              \
    e = __expf(G##10 - mx); s += e; ws += 10.f * e;                            \
    e = __expf(G##11 - mx); s += e; ws += 11.f * e;                            \
    e = __expf(G##12 - mx); s += e; ws += 12.f * e;                            \
    e = __expf(G##13 - mx); s += e; ws += 13.f * e;                            \
    e = __expf(G##14 - mx); s += e; ws += 14.f * e;                            \
    e = __expf(G##15 - mx); s += e; ws += 15.f * e;                            \
    OUT = ws * frcp(s);                                                        \
  }

// ---------------- kernel 1: decode via WAVE-PRIVATE async-LDS pipeline
// (global_load_lds + counted vmcnt, NO barriers in phase 1) + screen + top-10 ----------------
__global__ __launch_bounds__(256) void decode_topk_kernel(
    const float* __restrict__ boxes, const float* __restrict__ scores,
    const float* __restrict__ targets, unsigned int* __restrict__ iou_bits,
    uint2* __restrict__ cand, float* __restrict__ bcePartial,
    unsigned int* __restrict__ ctr, int N, int bpb) {
  const int tid = threadIdx.x;
  const int b = blockIdx.x / bpb;
  const int blk = blockIdx.x - b * bpb;
  const int a0 = blk * APB;
  const int w = tid >> 6;
  const int l = tid & 63;

  // 32KB: 4 waves x 2 bufs x 4KB tile, ALIASED with phase-2/3 heaps
  // (tile dead after phase 1; separated by the barrier below).
  __shared__ __align__(16) char u_raw[32768];
  float* s_hv = (float*)u_raw;                 // 10240B
  int* s_hi = (int*)(u_raw + 10240);           // 10240B
  uint2* s_mg = (uint2*)(u_raw + 20480);       // 5120B
  __shared__ float4 s_sv[APB];
  __shared__ float s_at[APB];
  __shared__ int s_ix[APB];
  __shared__ int s_cnt;
  __shared__ float s_bce;
  if (tid == 0) { s_cnt = 0; s_bce = 0.f; }
  if (blockIdx.x == 0 && tid == 0) *ctr = 0u;  // merge-done ctr; stream-ordered
  __syncthreads();

  const size_t Ns = (size_t)N;
  float* wbuf0 = (float*)(u_raw + w * 8192);
  float* wbuf1 = wbuf0 + 1024;

  // ---- phase 1 (wave-private, barrier-free, counted-vmcnt pipeline) ----
  // wave w owns anchors [a0+64w, a0+64w+64); lane l -> anchor column colc.
  const int n = a0 + tid;
  const int colc = min(a0 + w * 64 + l, N - 1);  // clamp: tail loads dup data
  const float* gl = boxes + (size_t)(b * 64) * Ns + colc;

  float e0, e1, e2, e3;
  G16(0, wbuf0)                   // rows 0-15  (side 0)
  G16(16, wbuf1)                  // rows 16-31 (side 1)
  WAITVM(16)                      // oldest 16 done -> buf0 ready
  { DECL_B(wbuf0, A) EV16(A, e0) }
  WAITLGKM()                      // buf0 reads complete before reuse
  G16(32, wbuf0)                  // rows 32-47 (side 2)
  WAITVM(16)                      // first 32 done -> buf1 ready
  { DECL_B(wbuf1, Bv) EV16(Bv, e1) }
  WAITLGKM()
  G16(48, wbuf1)                  // rows 48-63 (side 3)
  WAITVM(16)                      // first 48 done -> buf0 ready
  { DECL_B(wbuf0, Cv) EV16(Cv, e2) }
  WAITVM(0)                       // all done -> buf1 ready
  { DECL_B(wbuf1, Dv) EV16(Dv, e3) }

  float bce0 = 0.f;
  bool pred = false;
  float at = 0.f;
  if (n < N) {
    float w1 = e2 - e0, h1 = e3 - e1;
    if (w1 > 0.f && h1 > 0.f) {  // else ciou<=0 vs every target (ref masks topv>0)
      pred = true;
      at = atanf(w1 * frcp(h1 + EPSQ));
    }
    const size_t i = (size_t)b * N + n;
    iou_bits[i] = 0u;
    float sc = scores[i];
    bce0 = fmaxf(sc, 0.f) + log1pf(__expf(-fabsf(sc)));
  }
  // ballot compaction: one contended LDS atomic per wave (not per thread)
  {
    unsigned long long mask = __ballot(pred);
    int cnt = __popcll(mask);
    int bslot = 0;
    if (l == 0 && cnt) bslot = atomicAdd(&s_cnt, cnt);
    bslot = __shfl(bslot, 0, 64);
    if (pred) {
      int pos = bslot + __popcll(mask & ((1ull << l) - 1ull));
      s_sv[pos] = make_float4(e0, e1, e2, e3);
      s_at[pos] = at;
      s_ix[pos] = n;
    }
  }
#pragma unroll
  for (int d = 1; d < 64; d <<= 1) bce0 += __shfl_xor(bce0, d, 64);
  if (l == 0) atomicAdd(&s_bce, bce0);
  __syncthreads();  // tile dead from here; heap (s_hv/s_hi/s_mg) live
  const int nsurv = s_cnt;
  if (tid == 0) bcePartial[blockIdx.x] = s_bce;  // always written: no memset

  // ---- phase 2: lane = target; wave w scans its survivor quarter (LDS broadcast) ----
  const float4 t = ((const float4*)targets)[b * MQ + l];
  const float x21 = t.x, y21 = t.y, x22 = t.z, y22 = t.w;
  const float w2 = x22 - x21, h2 = y22 - y21;
  const float atan_t = atanf(w2 * frcp(h2 + EPSQ));
  const float area2 = w2 * h2, sumx2 = x21 + x22, sumy2 = y21 + y22;
  const float CPI = 4.0f / (float)(M_PI * M_PI);

  float hv0 = 0.f, hv1 = 0.f, hv2 = 0.f, hv3 = 0.f, hv4 = 0.f;
  float hv5 = 0.f, hv6 = 0.f, hv7 = 0.f, hv8 = 0.f, hv9 = 0.f;
  int hi0 = 0, hi1 = 0, hi2 = 0, hi3 = 0, hi4 = 0;
  int hi5 = 0, hi6 = 0, hi7 = 0, hi8 = 0, hi9 = 0;

  const int qlen = (nsurv + 3) >> 2;
  const int j0 = w * qlen;
  const int j1 = min(nsurv, j0 + qlen);
  for (int j = j0; j < j1; ++j) {
    float4 p = s_sv[j];  // same addr across lanes -> LDS broadcast
    float pa = s_at[j];
    int ixj = s_ix[j];
    float x11 = p.x, y11 = p.y, x12 = p.z, y12 = p.w;
    float w1 = x12 - x11, h1 = y12 - y11;
    float iw = fmaxf(fminf(x12, x22) - fmaxf(x11, x21), 0.f);
    float ih = fmaxf(fminf(y12, y22) - fmaxf(y11, y21), 0.f);
    float inter = iw * ih;
    float uni = w1 * h1 + area2 - inter + EPSQ;
    float iou = inter * frcp(uni);
    float cw = fmaxf(x12, x22) - fminf(x11, x21);
    float ch = fmaxf(y12, y22) - fminf(y11, y21);
    float c2 = cw * cw + ch * ch + EPSQ;
    float dx = sumx2 - x11 - x12;
    float dy = sumy2 - y11 - y12;
    float rho2 = (dx * dx + dy * dy) * 0.25f;
    float da = atan_t - pa;
    float v = CPI * da * da;
    float alpha = v * frcp(v - iou + 1.f + EPSQ);
    float ciou = iou - rho2 * frcp(c2) - alpha * v;
    if (ciou > hv9) {
      float cv = ciou;
      int ci = ixj;
#define INS(vk, ik)                         \
  {                                         \
    bool gt = cv > vk;                      \
    float tv_ = vk; int ti_ = ik;           \
    vk = gt ? cv : vk; ik = gt ? ci : ik;   \
    cv = gt ? tv_ : cv; ci = gt ? ti_ : ci; \
  }
      INS(hv0, hi0) INS(hv1, hi1) INS(hv2, hi2) INS(hv3, hi3) INS(hv4, hi4)
      INS(hv5, hi5) INS(hv6, hi6) INS(hv7, hi7) INS(hv8, hi8) INS(hv9, hi9)
#undef INS
    }
  }
  const int hb = (w * MQ + l) * KTOP;
  s_hv[hb + 0] = hv0; s_hi[hb + 0] = hi0;
  s_hv[hb + 1] = hv1; s_hi[hb + 1] = hi1;
  s_hv[hb + 2] = hv2; s_hi[hb + 2] = hi2;
  s_hv[hb + 3] = hv3; s_hi[hb + 3] = hi3;
  s_hv[hb + 4] = hv4; s_hi[hb + 4] = hi4;
  s_hv[hb + 5] = hv5; s_hi[hb + 5] = hi5;
  s_hv[hb + 6] = hv6; s_hi[hb + 6] = hi6;
  s_hv[hb + 7] = hv7; s_hi[hb + 7] = hi7;
  s_hv[hb + 8] = hv8; s_hi[hb + 8] = hi8;
  s_hv[hb + 9] = hv9; s_hi[hb + 9] = hi9;
  __syncthreads();

  // ---- phase 3: wave 0, lane m: 4-way merge -> s_mg ----
  if (w == 0) {
    const int m = l;
    int p0 = 0, p1 = 0, p2 = 0, p3 = 0;
    for (int r = 0; r < KTOP; ++r) {
      float c0 = s_hv[(0 * MQ + m) * KTOP + p0];
      float c1 = s_hv[(1 * MQ + m) * KTOP + p1];
      float c2m = s_hv[(2 * MQ + m) * KTOP + p2];
      float c3 = s_hv[(3 * MQ + m) * KTOP + p3];
      float best = c0; int bw = 0;
      if (c1 > best) { best = c1; bw = 1; }
      if (c2m > best) { best = c2m; bw = 2; }
      if (c3 > best) { best = c3; bw = 3; }
      int psel = (bw == 0) ? p0 : (bw == 1) ? p1 : (bw == 2) ? p2 : p3;
      int bidx = s_hi[(bw * MQ + m) * KTOP + psel];
      s_mg[m * KTOP + r] = make_uint2(__float_as_uint(best), (unsigned)bidx);
      if (bw == 0) p0 = min(p0 + 1, KTOP - 1);
      else if (bw == 1) p1 = min(p1 + 1, KTOP - 1);
      else if (bw == 2) p2 = min(p2 + 1, KTOP - 1);
      else p3 = min(p3 + 1, KTOP - 1);
    }
  }
  __syncthreads();
  // copy-out: CONTIGUOUS per-block store (merge takes the strided read side)
  uint2* obase = cand + (size_t)(b * bpb + blk) * (MQ * KTOP);
  for (int sl = tid; sl < MQ * KTOP; sl += 256) obase[sl] = s_mg[sl];
}

// ---------------- exact top-10 of LDS buffer (wave 0 only) ----------------
__device__ __forceinline__ void select_top10(
    float* s_bv, int* s_bi, float* s_winv, int* s_wini,
    int* s_cnt, int c, int tid) {
  if (tid < 64) {
    for (int r = 0; r < KTOP; ++r) {
      float bv = 0.f;
      int bs = 0xffff;
      for (int sl = tid; sl < c; sl += 64) {
        float v = s_bv[sl];
        if (v > bv) { bv = v; bs = sl; }
      }
      unsigned long long key =
          ((unsigned long long)__float_as_uint(bv) << 32) | (unsigned int)bs;
#pragma unroll
      for (int d = 1; d < 64; d <<= 1) {
        unsigned long long o = __shfl_xor(key, d, 64);
        if (o > key) key = o;
      }
      if (tid == 0) {
        float wv = __uint_as_float((unsigned int)(key >> 32));
        int ws = (int)(key & 0xffffu);
        s_winv[r] = wv;
        if (wv > 0.f && ws != 0xffff) {
          s_wini[r] = s_bi[ws];
          s_bv[ws] = 0.f;
        } else {
          s_wini[r] = 0;
        }
      }
    }
    if (tid < KTOP) { s_bv[tid] = s_winv[tid]; s_bi[tid] = s_wini[tid]; }
    if (tid == 0) *s_cnt = KTOP;
  }
}

// ---------------- kernel 2: merge 133x10 per (b,m) -> top-10; scatter + exact delta;
// last block finalizes with a parallel reduction ----------------
__global__ __launch_bounds__(256) void merge_kernel(
    const uint2* __restrict__ cand, const float* __restrict__ scores,
    unsigned int* __restrict__ iou_bits, const float* __restrict__ bcePartial,
    float* __restrict__ mergePartial, unsigned int* __restrict__ ctr,
    float* __restrict__ out, int N, int bpb) {
  const int bm = blockIdx.x;
  const int b = bm >> 6;
  const int m = bm & 63;
  const int tid = threadIdx.x;
  const int l = tid & 63;
  const int NC = bpb * KTOP;  // 1330 for N=34000

  __shared__ float s_bv[MBUF];
  __shared__ int s_bi[MBUF];
  __shared__ float s_winv[KTOP];
  __shared__ int s_wini[KTOP];
  __shared__ int s_cnt;
  __shared__ float s_d[3];
  __shared__ int s_last;
  __shared__ float s_acc[BQ * 3];  // finalize: {box_sum, npos, bce} per batch
  if (tid == 0) s_cnt = 0;
  if (tid < 3) s_d[tid] = 0.f;
  if (tid < BQ * 3) s_acc[tid] = 0.f;
  __syncthreads();

  // strided gather over decode blocks (cand in contiguous-per-block layout)
  for (int k2 = tid; k2 < NC; k2 += 256) {
    int blkk = k2 / KTOP;
    int r = k2 - blkk * KTOP;
    uint2 e = cand[((size_t)(b * bpb + blkk) * MQ + m) * KTOP + r];
    float v = __uint_as_float(e.x);
    bool p = v > 0.f;
    unsigned long long mask = __ballot(p);  // lane0 active whenever any lane is
    int cnt = __popcll(mask);
    int bslot = 0;
    if (l == 0 && cnt) bslot = atomicAdd(&s_cnt, cnt);
    bslot = __shfl(bslot, 0, 64);
    if (p) {
      int pos = bslot + __popcll(mask & ((1ull << l) - 1ull));
      s_bv[pos] = v;
      s_bi[pos] = (int)e.y;
    }
  }
  __syncthreads();
  int c = s_cnt;
  __syncthreads();
  if (c > KTOP) {
    select_top10(s_bv, s_bi, s_winv, s_wini, &s_cnt, c, tid);
    __syncthreads();
    c = KTOP;
  }
  if (tid < KTOP && tid < c) {
    float v = s_bv[tid];
    if (v > 0.f) {
      int ix = s_bi[tid];
      unsigned int vb = __float_as_uint(v);
      unsigned int old = atomicMax(&iou_bits[(size_t)b * N + ix], vb);
      if (old < vb) {  // raised this anchor's max: exact delta (telescopes)
        float vold = __uint_as_float(old);  // 0.f when old==0
        bool was = (old != 0u);
        atomicAdd(&s_d[0], was ? (vold - v) : (1.f - v));
        if (!was) atomicAdd(&s_d[1], 1.f);
        atomicAdd(&s_d[2], -scores[(size_t)b * N + ix] * (v - vold));
      }
    }
  }
  __syncthreads();
  if (tid == 0) {
    float4* mp = (float4*)(mergePartial + (size_t)bm * 4);
    *mp = make_float4(s_d[0], s_d[1], s_d[2], 0.f);  // always written
    __threadfence();                                  // release partials
    unsigned int done = atomicAdd(ctr, 1u);           // device-scope RMW
    s_last = (done == (unsigned)(gridDim.x - 1)) ? 1 : 0;
  }
  __syncthreads();
  if (s_last) {
    __threadfence();  // acquire: all other blocks' partials now visible
    volatile const float* mp = mergePartial;
    for (int i = tid; i < BQ * MQ; i += 256) {
      int bb = i >> 6;
      float a0 = mp[i * 4 + 0];
      float a1 = mp[i * 4 + 1];
      float a2 = mp[i * 4 + 2];
      atomicAdd(&s_acc[bb * 3 + 0], a0);
      atomicAdd(&s_acc[bb * 3 + 1], a1);
      atomicAdd(&s_acc[bb * 3 + 2], a2);
    }
    volatile const float* bp = bcePartial;
    for (int i = tid; i < BQ * bpb; i += 256) {
      int bb = i / bpb;
      atomicAdd(&s_acc[bb * 3 + 2], bp[i]);
    }
    __syncthreads();
    if (tid == 0) {
      float box = 0.f, obj = 0.f;
      for (int bb = 0; bb < BQ; ++bb) {
        float np = s_acc[bb * 3 + 1];
        box += (np > 0.f) ? s_acc[bb * 3 + 0] / fmaxf(np, 1.f) : 0.f;
        obj += s_acc[bb * 3 + 2] / (float)N;
      }
      out[0] = (7.5f * box + obj) / (float)BQ;
      out[1] = box;
      out[2] = obj;
    }
  }
}

extern "C" void kernel_launch(void* const* d_in, const int* in_sizes, int n_in,
                              void* d_out, int out_size, void* d_ws, size_t ws_size,
                              hipStream_t stream) {
  const float* boxes = (const float*)d_in[0];
  const float* scores = (const float*)d_in[1];
  const float* targets = (const float*)d_in[2];
  float* out = (float*)d_out;
  const int N = in_sizes[1] / BQ;  // scores is [B, N]

  const int bpb = (N + APB - 1) / APB;  // 133 for N=34000
  const int nblk = BQ * bpb;            // 1064 decode blocks

  char* ws = (char*)d_ws;
  size_t cand_bytes = (size_t)BQ * bpb * MQ * KTOP * sizeof(uint2);
  size_t iou_bytes = (size_t)BQ * N * sizeof(unsigned int);
  size_t bce_bytes = (((size_t)nblk * sizeof(float)) + 255) & ~(size_t)255;
  size_t mp_bytes = (size_t)BQ * MQ * 4 * sizeof(float);

  uint2* cand = (uint2*)ws;                    ws += cand_bytes;
  unsigned int* iou_bits = (unsigned int*)ws;  ws += iou_bytes;
  float* bcePartial = (float*)ws;              ws += bce_bytes;
  float* mergePartial = (float*)ws;            ws += mp_bytes;
  unsigned int* ctr = (unsigned int*)ws;

  // 2 dispatches: no memset (always-written per-block partials; ctr zeroed by
  // decode which fully precedes merge by stream order), no finalize dispatch
  // (folded into merge's last block, parallel-reduced).
  decode_topk_kernel<<<nblk, 256, 0, stream>>>(boxes, scores, targets,
                                               iou_bits, cand, bcePartial, ctr, N, bpb);
  merge_kernel<<<BQ * MQ, 256, 0, stream>>>(cand, scores, iou_bits, bcePartial,
                                            mergePartial, ctr, out, N, bpb);
}

// Round 7
// 143.053 us; speedup vs baseline: 1.0433x; 1.0110x over previous
//
#include <hip/hip_runtime.h>
#include <math.h>

#define BQ 8
#define MQ 64
#define KTOP 10
#define EPSQ 1e-7f
#define APB 256   // anchors per decode block (4 waves x 64 anchors)
#define MBUF 1344 // >= bpb*KTOP = 1330 for N=34000

__device__ __forceinline__ float frcp(float x) { return __builtin_amdgcn_rcpf(x); }

// async global->LDS, 16B/lane (global_load_lds_dwordx4): LDS dest = uniform
// base + lane*16 (HW); global src per-lane. One instruction = 1KB burst.
__device__ __forceinline__ void load_lds_16(const float* g, void* l) {
  __builtin_amdgcn_global_load_lds(
      (const __attribute__((address_space(1))) void*)g,
      (__attribute__((address_space(3))) void*)l, 16, 0, 0);
}

#define WAITVM(N)                                           \
  asm volatile("s_waitcnt vmcnt(" #N ")" ::: "memory");     \
  __builtin_amdgcn_sched_barrier(0);

#define WAITLGKM()                                          \
  asm volatile("s_waitcnt lgkmcnt(0)" ::: "memory");        \
  __builtin_amdgcn_sched_barrier(0);

// one side (16 rows x 64 anchors = 4KB) in 4 instructions of 1KB each.
// chunk c covers rows R0+4c..R0+4c+3: lane l -> row (l>>4), anchor 4*(l&15);
// LDS linear lane*16B reproduces row-major [16][64] exactly.
#define G4(R0, BUF)                                                         \
  {                                                                         \
    _Pragma("unroll") for (int c = 0; c < 4; ++c)                           \
        load_lds_16(glq + (size_t)((R0) + 4 * c) * Ns, (BUF) + c * 256);    \
    __builtin_amdgcn_sched_barrier(0);                                      \
  }

// 16 values of one side from the wave tile (lane-consecutive -> conflict-free)
#define DECL_B(BUF, G)                                                   \
  float G##0 = (BUF)[0 * 64 + l], G##1 = (BUF)[1 * 64 + l],              \
        G##2 = (BUF)[2 * 64 + l], G##3 = (BUF)[3 * 64 + l],              \
        G##4 = (BUF)[4 * 64 + l], G##5 = (BUF)[5 * 64 + l],              \
        G##6 = (BUF)[6 * 64 + l], G##7 = (BUF)[7 * 64 + l],              \
        G##8 = (BUF)[8 * 64 + l], G##9 = (BUF)[9 * 64 + l],              \
        G##10 = (BUF)[10 * 64 + l], G##11 = (BUF)[11 * 64 + l],          \
        G##12 = (BUF)[12 * 64 + l], G##13 = (BUF)[13 * 64 + l],          \
        G##14 = (BUF)[14 * 64 + l], G##15 = (BUF)[15 * 64 + l];

#define EV16(G, OUT)                                                           \
  {                                                                            \
    float mx = fmaxf(fmaxf(fmaxf(fmaxf(G##0, G##1), fmaxf(G##2, G##3)),        \
                           fmaxf(fmaxf(G##4, G##5), fmaxf(G##6, G##7))),       \
                     fmaxf(fmaxf(fmaxf(G##8, G##9), fmaxf(G##10, G##11)),      \
                           fmaxf(fmaxf(G##12, G##13), fmaxf(G##14, G##15))));  \
    float s = 0.f, ws = 0.f, e;                                                \
    e = __expf(G##0 - mx); s += e;                                             \
    e = __expf(G##1 - mx); s += e; ws += 1.f * e;                              \
    e = __expf(G##2 - mx); s += e; ws += 2.f * e;                              \
    e = __expf(G##3 - mx); s += e; ws += 3.f * e;                              \
    e = __expf(G##4 - mx); s += e; ws += 4.f * e;                              \
    e = __expf(G##5 - mx); s += e; ws += 5.f * e;                              \
    e = __expf(G##6 - mx); s += e; ws += 6.f * e;                              \
    e = __expf(G##7 - mx); s += e; ws += 7.f * e;                              \
    e = __expf(G##8 - mx); s += e; ws += 8.f * e;                              \
    e = __expf(G##9 - mx); s += e; ws += 9.f * e;                              \
    e = __expf(G##10 - mx); s += e; ws += 10.f * e;                            \
    e = __expf(G##11 - mx); s += e; ws += 11.f * e;                            \
    e = __expf(G##12 - mx); s += e; ws += 12.f * e;                            \
    e = __expf(G##13 - mx); s += e; ws += 13.f * e;                            \
    e = __expf(G##14 - mx); s += e; ws += 14.f * e;                            \
    e = __expf(G##15 - mx); s += e; ws += 15.f * e;                            \
    OUT = ws * frcp(s);                                                        \
  }

// ---------------- kernel 1: decode via WAVE-PRIVATE async-LDS pipeline,
// now with 16B-wide global_load_lds (4x fewer VMEM inst, 1KB bursts) ----------------
__global__ __launch_bounds__(256) void decode_topk_kernel(
    const float* __restrict__ boxes, const float* __restrict__ scores,
    const float* __restrict__ targets, unsigned int* __restrict__ iou_bits,
    uint2* __restrict__ cand, float* __restrict__ bcePartial,
    unsigned int* __restrict__ ctr, int N, int bpb) {
  const int tid = threadIdx.x;
  const int b = blockIdx.x / bpb;
  const int blk = blockIdx.x - b * bpb;
  const int a0 = blk * APB;
  const int w = tid >> 6;
  const int l = tid & 63;

  // 32KB: 4 waves x 2 bufs x 4KB tile, ALIASED with phase-2/3 heaps
  // (tile dead after phase 1; separated by the barrier below).
  __shared__ __align__(16) char u_raw[32768];
  float* s_hv = (float*)u_raw;                 // 10240B
  int* s_hi = (int*)(u_raw + 10240);           // 10240B
  uint2* s_mg = (uint2*)(u_raw + 20480);       // 5120B
  __shared__ float4 s_sv[APB];
  __shared__ float s_at[APB];
  __shared__ int s_ix[APB];
  __shared__ int s_cnt;
  __shared__ float s_bce;
  if (tid == 0) { s_cnt = 0; s_bce = 0.f; }
  if (blockIdx.x == 0 && tid == 0) *ctr = 0u;  // merge-done ctr; stream-ordered
  __syncthreads();

  const size_t Ns = (size_t)N;
  float* wbuf0 = (float*)(u_raw + w * 8192);
  float* wbuf1 = wbuf0 + 1024;

  // ---- phase 1 (wave-private, barrier-free, counted-vmcnt pipeline) ----
  // wave w owns anchors [a0+64w, a0+64w+64). 16B loads: lane l covers row
  // (l>>4) of each 4-row chunk at anchors 4*(l&15)..+4 (clamped at tail).
  const int n = a0 + tid;
  const int aw = a0 + w * 64;
  int acol = aw + ((l & 15) << 2) + ((l >> 4) == 0 ? 0 : 0);  // anchor col base
  acol = aw + ((l & 15) << 2);
  if (acol > N - 4) acol = N - 4;  // tail: in-bounds dup loads; pred guards
  const float* glq = boxes + (size_t)(b * 64 + (l >> 4)) * Ns + acol;

  float e0, e1, e2, e3;
  G4(0, wbuf0)                    // rows 0-15  (side 0), 4 inst
  G4(16, wbuf1)                   // rows 16-31 (side 1), 4 inst
  WAITVM(4)                       // oldest 4 done -> buf0 ready
  { DECL_B(wbuf0, A) EV16(A, e0) }
  WAITLGKM()                      // buf0 reads complete before reuse
  G4(32, wbuf0)                   // rows 32-47 (side 2)
  WAITVM(4)                       // -> buf1 ready
  { DECL_B(wbuf1, Bv) EV16(Bv, e1) }
  WAITLGKM()
  G4(48, wbuf1)                   // rows 48-63 (side 3)
  WAITVM(4)                       // -> buf0 ready
  { DECL_B(wbuf0, Cv) EV16(Cv, e2) }
  WAITVM(0)                       // all done -> buf1 ready
  { DECL_B(wbuf1, Dv) EV16(Dv, e3) }

  float bce0 = 0.f;
  bool pred = false;
  float at = 0.f;
  if (n < N) {
    float w1 = e2 - e0, h1 = e3 - e1;
    if (w1 > 0.f && h1 > 0.f) {  // else ciou<=0 vs every target (ref masks topv>0)
      pred = true;
      at = atanf(w1 * frcp(h1 + EPSQ));
    }
    const size_t i = (size_t)b * N + n;
    iou_bits[i] = 0u;
    float sc = scores[i];
    bce0 = fmaxf(sc, 0.f) + log1pf(__expf(-fabsf(sc)));
  }
  // ballot compaction: one contended LDS atomic per wave (not per thread)
  {
    unsigned long long mask = __ballot(pred);
    int cnt = __popcll(mask);
    int bslot = 0;
    if (l == 0 && cnt) bslot = atomicAdd(&s_cnt, cnt);
    bslot = __shfl(bslot, 0, 64);
    if (pred) {
      int pos = bslot + __popcll(mask & ((1ull << l) - 1ull));
      s_sv[pos] = make_float4(e0, e1, e2, e3);
      s_at[pos] = at;
      s_ix[pos] = n;
    }
  }
#pragma unroll
  for (int d = 1; d < 64; d <<= 1) bce0 += __shfl_xor(bce0, d, 64);
  if (l == 0) atomicAdd(&s_bce, bce0);
  __syncthreads();  // tile dead from here; heap (s_hv/s_hi/s_mg) live
  const int nsurv = s_cnt;
  if (tid == 0) bcePartial[blockIdx.x] = s_bce;  // always written: no memset

  // ---- phase 2: lane = target; wave w scans its survivor quarter (LDS broadcast) ----
  const float4 t = ((const float4*)targets)[b * MQ + l];
  const float x21 = t.x, y21 = t.y, x22 = t.z, y22 = t.w;
  const float w2 = x22 - x21, h2 = y22 - y21;
  const float atan_t = atanf(w2 * frcp(h2 + EPSQ));
  const float area2 = w2 * h2, sumx2 = x21 + x22, sumy2 = y21 + y22;
  const float CPI = 4.0f / (float)(M_PI * M_PI);

  float hv0 = 0.f, hv1 = 0.f, hv2 = 0.f, hv3 = 0.f, hv4 = 0.f;
  float hv5 = 0.f, hv6 = 0.f, hv7 = 0.f, hv8 = 0.f, hv9 = 0.f;
  int hi0 = 0, hi1 = 0, hi2 = 0, hi3 = 0, hi4 = 0;
  int hi5 = 0, hi6 = 0, hi7 = 0, hi8 = 0, hi9 = 0;

  const int qlen = (nsurv + 3) >> 2;
  const int j0 = w * qlen;
  const int j1 = min(nsurv, j0 + qlen);
  for (int j = j0; j < j1; ++j) {
    float4 p = s_sv[j];  // same addr across lanes -> LDS broadcast
    float pa = s_at[j];
    int ixj = s_ix[j];
    float x11 = p.x, y11 = p.y, x12 = p.z, y12 = p.w;
    float w1 = x12 - x11, h1 = y12 - y11;
    float iw = fmaxf(fminf(x12, x22) - fmaxf(x11, x21), 0.f);
    float ih = fmaxf(fminf(y12, y22) - fmaxf(y11, y21), 0.f);
    float inter = iw * ih;
    float uni = w1 * h1 + area2 - inter + EPSQ;
    float iou = inter * frcp(uni);
    float cw = fmaxf(x12, x22) - fminf(x11, x21);
    float ch = fmaxf(y12, y22) - fminf(y11, y21);
    float c2 = cw * cw + ch * ch + EPSQ;
    float dx = sumx2 - x11 - x12;
    float dy = sumy2 - y11 - y12;
    float rho2 = (dx * dx + dy * dy) * 0.25f;
    float da = atan_t - pa;
    float v = CPI * da * da;
    float alpha = v * frcp(v - iou + 1.f + EPSQ);
    float ciou = iou - rho2 * frcp(c2) - alpha * v;
    if (ciou > hv9) {
      float cv = ciou;
      int ci = ixj;
#define INS(vk, ik)                         \
  {                                         \
    bool gt = cv > vk;                      \
    float tv_ = vk; int ti_ = ik;           \
    vk = gt ? cv : vk; ik = gt ? ci : ik;   \
    cv = gt ? tv_ : cv; ci = gt ? ti_ : ci; \
  }
      INS(hv0, hi0) INS(hv1, hi1) INS(hv2, hi2) INS(hv3, hi3) INS(hv4, hi4)
      INS(hv5, hi5) INS(hv6, hi6) INS(hv7, hi7) INS(hv8, hi8) INS(hv9, hi9)
#undef INS
    }
  }
  const int hb = (w * MQ + l) * KTOP;
  s_hv[hb + 0] = hv0; s_hi[hb + 0] = hi0;
  s_hv[hb + 1] = hv1; s_hi[hb + 1] = hi1;
  s_hv[hb + 2] = hv2; s_hi[hb + 2] = hi2;
  s_hv[hb + 3] = hv3; s_hi[hb + 3] = hi3;
  s_hv[hb + 4] = hv4; s_hi[hb + 4] = hi4;
  s_hv[hb + 5] = hv5; s_hi[hb + 5] = hi5;
  s_hv[hb + 6] = hv6; s_hi[hb + 6] = hi6;
  s_hv[hb + 7] = hv7; s_hi[hb + 7] = hi7;
  s_hv[hb + 8] = hv8; s_hi[hb + 8] = hi8;
  s_hv[hb + 9] = hv9; s_hi[hb + 9] = hi9;
  __syncthreads();

  // ---- phase 3: wave 0, lane m: 4-way merge -> s_mg ----
  if (w == 0) {
    const int m = l;
    int p0 = 0, p1 = 0, p2 = 0, p3 = 0;
    for (int r = 0; r < KTOP; ++r) {
      float c0 = s_hv[(0 * MQ + m) * KTOP + p0];
      float c1 = s_hv[(1 * MQ + m) * KTOP + p1];
      float c2m = s_hv[(2 * MQ + m) * KTOP + p2];
      float c3 = s_hv[(3 * MQ + m) * KTOP + p3];
      float best = c0; int bw = 0;
      if (c1 > best) { best = c1; bw = 1; }
      if (c2m > best) { best = c2m; bw = 2; }
      if (c3 > best) { best = c3; bw = 3; }
      int psel = (bw == 0) ? p0 : (bw == 1) ? p1 : (bw == 2) ? p2 : p3;
      int bidx = s_hi[(bw * MQ + m) * KTOP + psel];
      s_mg[m * KTOP + r] = make_uint2(__float_as_uint(best), (unsigned)bidx);
      if (bw == 0) p0 = min(p0 + 1, KTOP - 1);
      else if (bw == 1) p1 = min(p1 + 1, KTOP - 1);
      else if (bw == 2) p2 = min(p2 + 1, KTOP - 1);
      else p3 = min(p3 + 1, KTOP - 1);
    }
  }
  __syncthreads();
  // copy-out: CONTIGUOUS per-block store (merge takes the strided read side)
  uint2* obase = cand + (size_t)(b * bpb + blk) * (MQ * KTOP);
  for (int sl = tid; sl < MQ * KTOP; sl += 256) obase[sl] = s_mg[sl];
}

// ---------------- exact top-10 of LDS buffer (wave 0 only) ----------------
__device__ __forceinline__ void select_top10(
    float* s_bv, int* s_bi, float* s_winv, int* s_wini,
    int* s_cnt, int c, int tid) {
  if (tid < 64) {
    for (int r = 0; r < KTOP; ++r) {
      float bv = 0.f;
      int bs = 0xffff;
      for (int sl = tid; sl < c; sl += 64) {
        float v = s_bv[sl];
        if (v > bv) { bv = v; bs = sl; }
      }
      unsigned long long key =
          ((unsigned long long)__float_as_uint(bv) << 32) | (unsigned int)bs;
#pragma unroll
      for (int d = 1; d < 64; d <<= 1) {
        unsigned long long o = __shfl_xor(key, d, 64);
        if (o > key) key = o;
      }
      if (tid == 0) {
        float wv = __uint_as_float((unsigned int)(key >> 32));
        int ws = (int)(key & 0xffffu);
        s_winv[r] = wv;
        if (wv > 0.f && ws != 0xffff) {
          s_wini[r] = s_bi[ws];
          s_bv[ws] = 0.f;
        } else {
          s_wini[r] = 0;
        }
      }
    }
    if (tid < KTOP) { s_bv[tid] = s_winv[tid]; s_bi[tid] = s_wini[tid]; }
    if (tid == 0) *s_cnt = KTOP;
  }
}

// ---------------- kernel 2: merge 133x10 per (b,m) -> top-10; scatter + exact delta;
// last block finalizes with a parallel reduction ----------------
__global__ __launch_bounds__(256) void merge_kernel(
    const uint2* __restrict__ cand, const float* __restrict__ scores,
    unsigned int* __restrict__ iou_bits, const float* __restrict__ bcePartial,
    float* __restrict__ mergePartial, unsigned int* __restrict__ ctr,
    float* __restrict__ out, int N, int bpb) {
  const int bm = blockIdx.x;
  const int b = bm >> 6;
  const int m = bm & 63;
  const int tid = threadIdx.x;
  const int l = tid & 63;
  const int NC = bpb * KTOP;  // 1330 for N=34000

  __shared__ float s_bv[MBUF];
  __shared__ int s_bi[MBUF];
  __shared__ float s_winv[KTOP];
  __shared__ int s_wini[KTOP];
  __shared__ int s_cnt;
  __shared__ float s_d[3];
  __shared__ int s_last;
  __shared__ float s_acc[BQ * 3];  // finalize: {box_sum, npos, bce} per batch
  if (tid == 0) s_cnt = 0;
  if (tid < 3) s_d[tid] = 0.f;
  if (tid < BQ * 3) s_acc[tid] = 0.f;
  __syncthreads();

  // strided gather over decode blocks (cand in contiguous-per-block layout)
  for (int k2 = tid; k2 < NC; k2 += 256) {
    int blkk = k2 / KTOP;
    int r = k2 - blkk * KTOP;
    uint2 e = cand[((size_t)(b * bpb + blkk) * MQ + m) * KTOP + r];
    float v = __uint_as_float(e.x);
    bool p = v > 0.f;
    unsigned long long mask = __ballot(p);  // lane0 active whenever any lane is
    int cnt = __popcll(mask);
    int bslot = 0;
    if (l == 0 && cnt) bslot = atomicAdd(&s_cnt, cnt);
    bslot = __shfl(bslot, 0, 64);
    if (p) {
      int pos = bslot + __popcll(mask & ((1ull << l) - 1ull));
      s_bv[pos] = v;
      s_bi[pos] = (int)e.y;
    }
  }
  __syncthreads();
  int c = s_cnt;
  __syncthreads();
  if (c > KTOP) {
    select_top10(s_bv, s_bi, s_winv, s_wini, &s_cnt, c, tid);
    __syncthreads();
    c = KTOP;
  }
  if (tid < KTOP && tid < c) {
    float v = s_bv[tid];
    if (v > 0.f) {
      int ix = s_bi[tid];
      unsigned int vb = __float_as_uint(v);
      unsigned int old = atomicMax(&iou_bits[(size_t)b * N + ix], vb);
      if (old < vb) {  // raised this anchor's max: exact delta (telescopes)
        float vold = __uint_as_float(old);  // 0.f when old==0
        bool was = (old != 0u);
        atomicAdd(&s_d[0], was ? (vold - v) : (1.f - v));
        if (!was) atomicAdd(&s_d[1], 1.f);
        atomicAdd(&s_d[2], -scores[(size_t)b * N + ix] * (v - vold));
      }
    }
  }
  __syncthreads();
  if (tid == 0) {
    float4* mp = (float4*)(mergePartial + (size_t)bm * 4);
    *mp = make_float4(s_d[0], s_d[1], s_d[2], 0.f);  // always written
    __threadfence();                                  // release partials
    unsigned int done = atomicAdd(ctr, 1u);           // device-scope RMW
    s_last = (done == (unsigned)(gridDim.x - 1)) ? 1 : 0;
  }
  __syncthreads();
  if (s_last) {
    __threadfence();  // acquire: all other blocks' partials now visible
    volatile const float* mp = mergePartial;
    for (int i = tid; i < BQ * MQ; i += 256) {
      int bb = i >> 6;
      float a0 = mp[i * 4 + 0];
      float a1 = mp[i * 4 + 1];
      float a2 = mp[i * 4 + 2];
      atomicAdd(&s_acc[bb * 3 + 0], a0);
      atomicAdd(&s_acc[bb * 3 + 1], a1);
      atomicAdd(&s_acc[bb * 3 + 2], a2);
    }
    volatile const float* bp = bcePartial;
    for (int i = tid; i < BQ * bpb; i += 256) {
      int bb = i / bpb;
      atomicAdd(&s_acc[bb * 3 + 2], bp[i]);
    }
    __syncthreads();
    if (tid == 0) {
      float box = 0.f, obj = 0.f;
      for (int bb = 0; bb < BQ; ++bb) {
        float np = s_acc[bb * 3 + 1];
        box += (np > 0.f) ? s_acc[bb * 3 + 0] / fmaxf(np, 1.f) : 0.f;
        obj += s_acc[bb * 3 + 2] / (float)N;
      }
      out[0] = (7.5f * box + obj) / (float)BQ;
      out[1] = box;
      out[2] = obj;
    }
  }
}

extern "C" void kernel_launch(void* const* d_in, const int* in_sizes, int n_in,
                              void* d_out, int out_size, void* d_ws, size_t ws_size,
                              hipStream_t stream) {
  const float* boxes = (const float*)d_in[0];
  const float* scores = (const float*)d_in[1];
  const float* targets = (const float*)d_in[2];
  float* out = (float*)d_out;
  const int N = in_sizes[1] / BQ;  // scores is [B, N]

  const int bpb = (N + APB - 1) / APB;  // 133 for N=34000
  const int nblk = BQ * bpb;            // 1064 decode blocks

  char* ws = (char*)d_ws;
  size_t cand_bytes = (size_t)BQ * bpb * MQ * KTOP * sizeof(uint2);
  size_t iou_bytes = (size_t)BQ * N * sizeof(unsigned int);
  size_t bce_bytes = (((size_t)nblk * sizeof(float)) + 255) & ~(size_t)255;
  size_t mp_bytes = (size_t)BQ * MQ * 4 * sizeof(float);

  uint2* cand = (uint2*)ws;                    ws += cand_bytes;
  unsigned int* iou_bits = (unsigned int*)ws;  ws += iou_bytes;
  float* bcePartial = (float*)ws;              ws += bce_bytes;
  float* mergePartial = (float*)ws;            ws += mp_bytes;
  unsigned int* ctr = (unsigned int*)ws;

  // 2 dispatches: no memset (always-written per-block partials; ctr zeroed by
  // decode which fully precedes merge by stream order), no finalize dispatch
  // (folded into merge's last block, parallel-reduced).
  decode_topk_kernel<<<nblk, 256, 0, stream>>>(boxes, scores, targets,
                                               iou_bits, cand, bcePartial, ctr, N, bpb);
  merge_kernel<<<BQ * MQ, 256, 0, stream>>>(cand, scores, iou_bits, bcePartial,
                                            mergePartial, ctr, out, N, bpb);
}

// Round 9
// 140.495 us; speedup vs baseline: 1.0623x; 1.0182x over previous
//
#include <hip/hip_runtime.h>
#include <math.h>

#define BQ 8
#define MQ 64
#define KTOP 10
#define EPSQ 1e-7f
#define APB 512   // anchors per decode block (256 threads x 2) -> 536 blocks (<=768 capacity)
#define MBUF 1344 // >= bpb*KTOP = 670 for N=34000

__device__ __forceinline__ float frcp(float x) { return __builtin_amdgcn_rcpf(x); }

// ---------------- kernel 1: decode via SIDE-TILE staging ----------------
// Stage one DFL side at a time: [16 rows x 512 anchors] = 32KB, 2KB contiguous
// per row (2x the page locality of prior variants). 3 blocks/CU -> grid of 536
// fits in ONE co-residency generation (prior rounds: 1064 blocks vs 1024
// capacity = a full 2x from the 40-block tail generation).
__global__ __launch_bounds__(256) void decode_topk_kernel(
    const float* __restrict__ boxes, const float* __restrict__ scores,
    const float* __restrict__ targets, unsigned int* __restrict__ iou_bits,
    uint2* __restrict__ cand, float* __restrict__ bcePartial,
    unsigned int* __restrict__ ctr, int N, int bpb) {
  const int tid = threadIdx.x;
  const int b = blockIdx.x / bpb;
  const int blk = blockIdx.x - b * bpb;
  const int a0 = blk * APB;
  const int w = tid >> 6;
  const int l = tid & 63;

  // 32KB stage tile, ALIASED with phase-2/3 heaps (temporally disjoint).
  __shared__ __align__(16) char u_raw[16 * APB * sizeof(float)];  // 32768
  float(*tile)[APB] = (float(*)[APB])u_raw;
  float* s_hv = (float*)u_raw;              // 10240B
  int* s_hi = (int*)(u_raw + 10240);        // 10240B
  uint2* s_mg = (uint2*)(u_raw + 20480);    // 5120B
  __shared__ float4 s_sv[APB];              // survivors: live ph1-end..ph2
  __shared__ float s_at[APB];
  __shared__ int s_ix[APB];
  __shared__ int s_cnt;
  __shared__ float s_bce;
  if (tid == 0) { s_cnt = 0; s_bce = 0.f; }
  if (blockIdx.x == 0 && tid == 0) *ctr = 0u;  // merge-done ctr; stream-ordered
  __syncthreads();

  const size_t Ns = (size_t)N;
  const int n0 = a0 + 2 * tid;  // this thread's 2 anchors
  const bool tail = (a0 + APB > N);

  // ---- early BCE + iou init for both anchors ----
  float bce0 = 0.f;
  if (n0 < N) {
    const size_t i = (size_t)b * N + n0;
    if (n0 + 1 < N && ((i & 1) == 0)) {
      iou_bits[i] = 0u; iou_bits[i + 1] = 0u;
      float2 sc = *(const float2*)(scores + i);
      bce0 = fmaxf(sc.x, 0.f) + log1pf(__expf(-fabsf(sc.x))) +
             fmaxf(sc.y, 0.f) + log1pf(__expf(-fabsf(sc.y)));
    } else if (n0 + 1 < N) {
      iou_bits[i] = 0u; iou_bits[i + 1] = 0u;
      float sa = scores[i], sb = scores[i + 1];
      bce0 = fmaxf(sa, 0.f) + log1pf(__expf(-fabsf(sa))) +
             fmaxf(sb, 0.f) + log1pf(__expf(-fabsf(sb)));
    } else {
      iou_bits[i] = 0u;
      float sc = scores[i];
      bce0 = fmaxf(sc, 0.f) + log1pf(__expf(-fabsf(sc)));
    }
  }

  // ---- phase 1: 4 sides; per side: coalesced stage (2KB/row) -> EV x2 ----
  const int tcol = 2 * tid;
  float ev_a[4], ev_b[4];  // statically indexed (full unroll)
#pragma unroll
  for (int s = 0; s < 4; ++s) {
    const float* gside = boxes + (size_t)(b * 64 + s * 16) * Ns;
    if (!tail) {
#pragma unroll
      for (int k = 0; k < 8; ++k) {
        int idx = tid + (k << 8);
        int r = idx >> 7;
        int c = (idx & 127) << 2;
        *(float4*)&tile[r][c] = *(const float4*)(gside + (size_t)r * Ns + a0 + c);
      }
    } else {
#pragma unroll
      for (int k = 0; k < 8; ++k) {
        int idx = tid + (k << 8);
        int r = idx >> 7;
        int c = (idx & 127) << 2;
        int gc = a0 + c;
        if (gc > N - 4) gc = N - 4;  // dup-clamp: invalid anchors pred-guarded
        if (gc < 0) gc = 0;
        *(float4*)&tile[r][c] = *(const float4*)(gside + (size_t)r * Ns + gc);
      }
    }
    __syncthreads();
    // two interleaved softmax-EV chains from LDS (float2 per row)
    float2 x0 = *(const float2*)&tile[0][tcol];
    float2 x1 = *(const float2*)&tile[1][tcol];
    float2 x2 = *(const float2*)&tile[2][tcol];
    float2 x3 = *(const float2*)&tile[3][tcol];
    float2 x4 = *(const float2*)&tile[4][tcol];
    float2 x5 = *(const float2*)&tile[5][tcol];
    float2 x6 = *(const float2*)&tile[6][tcol];
    float2 x7 = *(const float2*)&tile[7][tcol];
    float2 x8 = *(const float2*)&tile[8][tcol];
    float2 x9 = *(const float2*)&tile[9][tcol];
    float2 x10 = *(const float2*)&tile[10][tcol];
    float2 x11 = *(const float2*)&tile[11][tcol];
    float2 x12 = *(const float2*)&tile[12][tcol];
    float2 x13 = *(const float2*)&tile[13][tcol];
    float2 x14 = *(const float2*)&tile[14][tcol];
    float2 x15 = *(const float2*)&tile[15][tcol];
    float mxa = fmaxf(fmaxf(fmaxf(fmaxf(x0.x, x1.x), fmaxf(x2.x, x3.x)),
                            fmaxf(fmaxf(x4.x, x5.x), fmaxf(x6.x, x7.x))),
                      fmaxf(fmaxf(fmaxf(x8.x, x9.x), fmaxf(x10.x, x11.x)),
                            fmaxf(fmaxf(x12.x, x13.x), fmaxf(x14.x, x15.x))));
    float mxb = fmaxf(fmaxf(fmaxf(fmaxf(x0.y, x1.y), fmaxf(x2.y, x3.y)),
                            fmaxf(fmaxf(x4.y, x5.y), fmaxf(x6.y, x7.y))),
                      fmaxf(fmaxf(fmaxf(x8.y, x9.y), fmaxf(x10.y, x11.y)),
                            fmaxf(fmaxf(x12.y, x13.y), fmaxf(x14.y, x15.y))));
    float sa = 0.f, wa = 0.f, sb = 0.f, wb = 0.f, e;
#define STEP(K, XK)                                    \
    e = __expf(XK.x - mxa); sa += e; wa += (float)K * e; \
    e = __expf(XK.y - mxb); sb += e; wb += (float)K * e;
    STEP(0, x0) STEP(1, x1) STEP(2, x2) STEP(3, x3)
    STEP(4, x4) STEP(5, x5) STEP(6, x6) STEP(7, x7)
    STEP(8, x8) STEP(9, x9) STEP(10, x10) STEP(11, x11)
    STEP(12, x12) STEP(13, x13) STEP(14, x14) STEP(15, x15)
#undef STEP
    ev_a[s] = wa * frcp(sa);
    ev_b[s] = wb * frcp(sb);
    __syncthreads();  // tile reads done before restage / heap use
  }

  // ---- screen + ballot compaction (two rounds: anchor n0, n0+1) ----
  {
    bool pa = false, pb = false;
    float ata = 0.f, atb = 0.f;
    if (n0 < N) {
      float w1 = ev_a[2] - ev_a[0], h1 = ev_a[3] - ev_a[1];
      if (w1 > 0.f && h1 > 0.f) { pa = true; ata = atanf(w1 * frcp(h1 + EPSQ)); }
    }
    if (n0 + 1 < N) {
      float w1 = ev_b[2] - ev_b[0], h1 = ev_b[3] - ev_b[1];
      if (w1 > 0.f && h1 > 0.f) { pb = true; atb = atanf(w1 * frcp(h1 + EPSQ)); }
    }
    unsigned long long ma = __ballot(pa);
    int ca = __popcll(ma);
    int sa_ = 0;
    if (l == 0 && ca) sa_ = atomicAdd(&s_cnt, ca);
    sa_ = __shfl(sa_, 0, 64);
    if (pa) {
      int pos = sa_ + __popcll(ma & ((1ull << l) - 1ull));
      s_sv[pos] = make_float4(ev_a[0], ev_a[1], ev_a[2], ev_a[3]);
      s_at[pos] = ata;
      s_ix[pos] = n0;
    }
    unsigned long long mb = __ballot(pb);
    int cb = __popcll(mb);
    int sb_ = 0;
    if (l == 0 && cb) sb_ = atomicAdd(&s_cnt, cb);
    sb_ = __shfl(sb_, 0, 64);
    if (pb) {
      int pos = sb_ + __popcll(mb & ((1ull << l) - 1ull));
      s_sv[pos] = make_float4(ev_b[0], ev_b[1], ev_b[2], ev_b[3]);
      s_at[pos] = atb;
      s_ix[pos] = n0 + 1;
    }
  }
#pragma unroll
  for (int d = 1; d < 64; d <<= 1) bce0 += __shfl_xor(bce0, d, 64);
  if (l == 0) atomicAdd(&s_bce, bce0);
  __syncthreads();
  const int nsurv = s_cnt;
  if (tid == 0) bcePartial[blockIdx.x] = s_bce;  // always written: no memset

  // ---- phase 2: lane = target; wave w scans its survivor quarter ----
  const float4 t = ((const float4*)targets)[b * MQ + l];
  const float x21 = t.x, y21 = t.y, x22 = t.z, y22 = t.w;
  const float w2 = x22 - x21, h2 = y22 - y21;
  const float atan_t = atanf(w2 * frcp(h2 + EPSQ));
  const float area2 = w2 * h2, sumx2 = x21 + x22, sumy2 = y21 + y22;
  const float CPI = 4.0f / (float)(M_PI * M_PI);

  float hv0 = 0.f, hv1 = 0.f, hv2 = 0.f, hv3 = 0.f, hv4 = 0.f;
  float hv5 = 0.f, hv6 = 0.f, hv7 = 0.f, hv8 = 0.f, hv9 = 0.f;
  int hi0 = 0, hi1 = 0, hi2 = 0, hi3 = 0, hi4 = 0;
  int hi5 = 0, hi6 = 0, hi7 = 0, hi8 = 0, hi9 = 0;

  const int qlen = (nsurv + 3) >> 2;
  const int j0 = w * qlen;
  const int j1 = min(nsurv, j0 + qlen);
  for (int j = j0; j < j1; ++j) {
    float4 p = s_sv[j];  // same addr across lanes -> LDS broadcast
    float pa = s_at[j];
    int ixj = s_ix[j];
    float x11 = p.x, y11 = p.y, x12 = p.z, y12 = p.w;
    float w1 = x12 - x11, h1 = y12 - y11;
    float iw = fmaxf(fminf(x12, x22) - fmaxf(x11, x21), 0.f);
    float ih = fmaxf(fminf(y12, y22) - fmaxf(y11, y21), 0.f);
    float inter = iw * ih;
    float uni = w1 * h1 + area2 - inter + EPSQ;
    float iou = inter * frcp(uni);
    float cw = fmaxf(x12, x22) - fminf(x11, x21);
    float ch = fmaxf(y12, y22) - fminf(y11, y21);
    float c2 = cw * cw + ch * ch + EPSQ;
    float dx = sumx2 - x11 - x12;
    float dy = sumy2 - y11 - y12;
    float rho2 = (dx * dx + dy * dy) * 0.25f;
    float da = atan_t - pa;
    float v = CPI * da * da;
    float alpha = v * frcp(v - iou + 1.f + EPSQ);
    float ciou = iou - rho2 * frcp(c2) - alpha * v;
    if (ciou > hv9) {
      float cv = ciou;
      int ci = ixj;
#define INS(vk, ik)                         \
  {                                         \
    bool gt = cv > vk;                      \
    float tv_ = vk; int ti_ = ik;           \
    vk = gt ? cv : vk; ik = gt ? ci : ik;   \
    cv = gt ? tv_ : cv; ci = gt ? ti_ : ci; \
  }
      INS(hv0, hi0) INS(hv1, hi1) INS(hv2, hi2) INS(hv3, hi3) INS(hv4, hi4)
      INS(hv5, hi5) INS(hv6, hi6) INS(hv7, hi7) INS(hv8, hi8) INS(hv9, hi9)
#undef INS
    }
  }
  const int hb = (w * MQ + l) * KTOP;
  s_hv[hb + 0] = hv0; s_hi[hb + 0] = hi0;
  s_hv[hb + 1] = hv1; s_hi[hb + 1] = hi1;
  s_hv[hb + 2] = hv2; s_hi[hb + 2] = hi2;
  s_hv[hb + 3] = hv3; s_hi[hb + 3] = hi3;
  s_hv[hb + 4] = hv4; s_hi[hb + 4] = hi4;
  s_hv[hb + 5] = hv5; s_hi[hb + 5] = hi5;
  s_hv[hb + 6] = hv6; s_hi[hb + 6] = hi6;
  s_hv[hb + 7] = hv7; s_hi[hb + 7] = hi7;
  s_hv[hb + 8] = hv8; s_hi[hb + 8] = hi8;
  s_hv[hb + 9] = hv9; s_hi[hb + 9] = hi9;
  __syncthreads();

  // ---- phase 3: wave 0, lane m: 4-way merge -> s_mg ----
  if (w == 0) {
    const int m = l;
    int p0 = 0, p1 = 0, p2 = 0, p3 = 0;
    for (int r = 0; r < KTOP; ++r) {
      float c0 = s_hv[(0 * MQ + m) * KTOP + p0];
      float c1 = s_hv[(1 * MQ + m) * KTOP + p1];
      float c2m = s_hv[(2 * MQ + m) * KTOP + p2];
      float c3 = s_hv[(3 * MQ + m) * KTOP + p3];
      float best = c0; int bw = 0;
      if (c1 > best) { best = c1; bw = 1; }
      if (c2m > best) { best = c2m; bw = 2; }
      if (c3 > best) { best = c3; bw = 3; }
      int psel = (bw == 0) ? p0 : (bw == 1) ? p1 : (bw == 2) ? p2 : p3;
      int bidx = s_hi[(bw * MQ + m) * KTOP + psel];
      s_mg[m * KTOP + r] = make_uint2(__float_as_uint(best), (unsigned)bidx);
      if (bw == 0) p0 = min(p0 + 1, KTOP - 1);
      else if (bw == 1) p1 = min(p1 + 1, KTOP - 1);
      else if (bw == 2) p2 = min(p2 + 1, KTOP - 1);
      else p3 = min(p3 + 1, KTOP - 1);
    }
  }
  __syncthreads();
  // copy-out: CONTIGUOUS per-block store (merge takes the strided read side)
  uint2* obase = cand + (size_t)(b * bpb + blk) * (MQ * KTOP);
  for (int sl = tid; sl < MQ * KTOP; sl += 256) obase[sl] = s_mg[sl];
}

// ---------------- exact top-10 of LDS buffer (wave 0 only) ----------------
__device__ __forceinline__ void select_top10(
    float* s_bv, int* s_bi, float* s_winv, int* s_wini,
    int* s_cnt, int c, int tid) {
  if (tid < 64) {
    for (int r = 0; r < KTOP; ++r) {
      float bv = 0.f;
      int bs = 0xffff;
      for (int sl = tid; sl < c; sl += 64) {
        float v = s_bv[sl];
        if (v > bv) { bv = v; bs = sl; }
      }
      unsigned long long key =
          ((unsigned long long)__float_as_uint(bv) << 32) | (unsigned int)bs;
#pragma unroll
      for (int d = 1; d < 64; d <<= 1) {
        unsigned long long o = __shfl_xor(key, d, 64);
        if (o > key) key = o;
      }
      if (tid == 0) {
        float wv = __uint_as_float((unsigned int)(key >> 32));
        int ws = (int)(key & 0xffffu);
        s_winv[r] = wv;
        if (wv > 0.f && ws != 0xffff) {
          s_wini[r] = s_bi[ws];
          s_bv[ws] = 0.f;
        } else {
          s_wini[r] = 0;
        }
      }
    }
    if (tid < KTOP) { s_bv[tid] = s_winv[tid]; s_bi[tid] = s_wini[tid]; }
    if (tid == 0) *s_cnt = KTOP;
  }
}

// ---------------- kernel 2: merge 67x10 per (b,m) -> top-10; scatter + exact delta;
// last block finalizes with a parallel reduction ----------------
__global__ __launch_bounds__(256) void merge_kernel(
    const uint2* __restrict__ cand, const float* __restrict__ scores,
    unsigned int* __restrict__ iou_bits, const float* __restrict__ bcePartial,
    float* __restrict__ mergePartial, unsigned int* __restrict__ ctr,
    float* __restrict__ out, int N, int bpb) {
  const int bm = blockIdx.x;
  const int b = bm >> 6;
  const int m = bm & 63;
  const int tid = threadIdx.x;
  const int l = tid & 63;
  const int NC = bpb * KTOP;  // 670 for N=34000

  __shared__ float s_bv[MBUF];
  __shared__ int s_bi[MBUF];
  __shared__ float s_winv[KTOP];
  __shared__ int s_wini[KTOP];
  __shared__ int s_cnt;
  __shared__ float s_d[3];
  __shared__ int s_last;
  __shared__ float s_acc[BQ * 3];  // finalize: {box_sum, npos, bce} per batch
  if (tid == 0) s_cnt = 0;
  if (tid < 3) s_d[tid] = 0.f;
  if (tid < BQ * 3) s_acc[tid] = 0.f;
  __syncthreads();

  // strided gather over decode blocks (cand in contiguous-per-block layout)
  for (int k2 = tid; k2 < NC; k2 += 256) {
    int blkk = k2 / KTOP;
    int r = k2 - blkk * KTOP;
    uint2 e = cand[((size_t)(b * bpb + blkk) * MQ + m) * KTOP + r];
    float v = __uint_as_float(e.x);
    bool p = v > 0.f;
    unsigned long long mask = __ballot(p);  // lane0 active whenever any lane is
    int cnt = __popcll(mask);
    int bslot = 0;
    if (l == 0 && cnt) bslot = atomicAdd(&s_cnt, cnt);
    bslot = __shfl(bslot, 0, 64);
    if (p) {
      int pos = bslot + __popcll(mask & ((1ull << l) - 1ull));
      s_bv[pos] = v;
      s_bi[pos] = (int)e.y;
    }
  }
  __syncthreads();
  int c = s_cnt;
  __syncthreads();
  if (c > KTOP) {
    select_top10(s_bv, s_bi, s_winv, s_wini, &s_cnt, c, tid);
    __syncthreads();
    c = KTOP;
  }
  if (tid < KTOP && tid < c) {
    float v = s_bv[tid];
    if (v > 0.f) {
      int ix = s_bi[tid];
      unsigned int vb = __float_as_uint(v);
      unsigned int old = atomicMax(&iou_bits[(size_t)b * N + ix], vb);
      if (old < vb) {  // raised this anchor's max: exact delta (telescopes)
        float vold = __uint_as_float(old);  // 0.f when old==0
        bool was = (old != 0u);
        atomicAdd(&s_d[0], was ? (vold - v) : (1.f - v));
        if (!was) atomicAdd(&s_d[1], 1.f);
        atomicAdd(&s_d[2], -scores[(size_t)b * N + ix] * (v - vold));
      }
    }
  }
  __syncthreads();
  if (tid == 0) {
    float4* mp = (float4*)(mergePartial + (size_t)bm * 4);
    *mp = make_float4(s_d[0], s_d[1], s_d[2], 0.f);  // always written
    __threadfence();                                  // release partials
    unsigned int done = atomicAdd(ctr, 1u);           // device-scope RMW
    s_last = (done == (unsigned)(gridDim.x - 1)) ? 1 : 0;
  }
  __syncthreads();
  if (s_last) {
    __threadfence();  // acquire: all other blocks' partials now visible
    volatile const float* mp = mergePartial;
    for (int i = tid; i < BQ * MQ; i += 256) {
      int bb = i >> 6;
      float a0 = mp[i * 4 + 0];
      float a1 = mp[i * 4 + 1];
      float a2 = mp[i * 4 + 2];
      atomicAdd(&s_acc[bb * 3 + 0], a0);
      atomicAdd(&s_acc[bb * 3 + 1], a1);
      atomicAdd(&s_acc[bb * 3 + 2], a2);
    }
    volatile const float* bp = bcePartial;
    for (int i = tid; i < BQ * bpb; i += 256) {
      int bb = i / bpb;
      atomicAdd(&s_acc[bb * 3 + 2], bp[i]);
    }
    __syncthreads();
    if (tid == 0) {
      float box = 0.f, obj = 0.f;
      for (int bb = 0; bb < BQ; ++bb) {
        float np = s_acc[bb * 3 + 1];
        box += (np > 0.f) ? s_acc[bb * 3 + 0] / fmaxf(np, 1.f) : 0.f;
        obj += s_acc[bb * 3 + 2] / (float)N;
      }
      out[0] = (7.5f * box + obj) / (float)BQ;
      out[1] = box;
      out[2] = obj;
    }
  }
}

extern "C" void kernel_launch(void* const* d_in, const int* in_sizes, int n_in,
                              void* d_out, int out_size, void* d_ws, size_t ws_size,
                              hipStream_t stream) {
  const float* boxes = (const float*)d_in[0];
  const float* scores = (const float*)d_in[1];
  const float* targets = (const float*)d_in[2];
  float* out = (float*)d_out;
  const int N = in_sizes[1] / BQ;  // scores is [B, N]

  const int bpb = (N + APB - 1) / APB;  // 67 for N=34000
  const int nblk = BQ * bpb;            // 536 decode blocks (<= 768 capacity)

  char* ws = (char*)d_ws;
  size_t cand_bytes = (size_t)BQ * bpb * MQ * KTOP * sizeof(uint2);
  size_t iou_bytes = (size_t)BQ * N * sizeof(unsigned int);
  size_t bce_bytes = (((size_t)nblk * sizeof(float)) + 255) & ~(size_t)255;
  size_t mp_bytes = (size_t)BQ * MQ * 4 * sizeof(float);

  uint2* cand = (uint2*)ws;                    ws += cand_bytes;
  unsigned int* iou_bits = (unsigned int*)ws;  ws += iou_bytes;
  float* bcePartial = (float*)ws;              ws += bce_bytes;
  float* mergePartial = (float*)ws;            ws += mp_bytes;
  unsigned int* ctr = (unsigned int*)ws;

  // 2 dispatches: no memset (always-written per-block partials; ctr zeroed by
  // decode which fully precedes merge by stream order), no finalize dispatch
  // (folded into merge's last block, parallel-reduced).
  decode_topk_kernel<<<nblk, 256, 0, stream>>>(boxes, scores, targets,
                                               iou_bits, cand, bcePartial, ctr, N, bpb);
  merge_kernel<<<BQ * MQ, 256, 0, stream>>>(cand, scores, iou_bits, bcePartial,
                                            mergePartial, ctr, out, N, bpb);
}